// Round 1
// 593.528 us; speedup vs baseline: 1.3848x; 1.3848x over previous
//
#include <hip/hip_runtime.h>
#include <hip/hip_bf16.h>

typedef __hip_bfloat16 bf16;
typedef __attribute__((ext_vector_type(8))) short short8;
typedef __attribute__((ext_vector_type(4))) float float4v;

#define B_   2
#define C_   128
#define H_   256
#define W_   256
#define HW_  65536
#define HD_  8
#define CH_  16
#define C3_  384

static __device__ __forceinline__ float b2f(bf16 v) { return __bfloat162float(v); }
static __device__ __forceinline__ bf16  f2b(float v) { return __float2bfloat16(v); }
static __device__ __forceinline__ short b2s(bf16 v) { return *reinterpret_cast<short*>(&v); }

// ---------------------------------------------------------------- weight prep
// adds: qkv weights as bf16, layout [o][k] with the gram-style XOR swizzle
// baked in (chunk ^= (o&7)) so the GEMM kernel's A-tile stage is a linear copy.
__global__ void k_wprep(const float* __restrict__ qkv_w, const float* __restrict__ proj_w,
                        const float* __restrict__ sa_w1,
                        float* __restrict__ wt_qkvT, float* __restrict__ wt_proj,
                        float* __restrict__ wt_sa1, bf16* __restrict__ wt_qkv_bf,
                        int do_bf) {
  int idx = blockIdx.x * 256 + threadIdx.x;
  if (idx < C3_ * C_) { int o = idx / C_, i = idx % C_; wt_qkvT[i * C3_ + o] = qkv_w[idx]; }
  if (idx < C_ * C_)  { int o = idx / C_, i = idx % C_; wt_proj[i * C_ + o] = proj_w[idx]; }
  if (idx < 16 * C_)  { int j = idx / C_, i = idx % C_; wt_sa1[i * 16 + j] = sa_w1[idx]; }
  if (do_bf && idx < C3_ * C_) {
    int o = idx / C_, k = idx % C_;
    int sk = ((((k >> 3) ^ (o & 7)) << 3) | (k & 7));
    wt_qkv_bf[o * C_ + sk] = f2b(qkv_w[idx]);
  }
}

// ------------------------------------------------- spatial gate sa (2 pos/thr)
__global__ void __launch_bounds__(256) k_sa(
    const float* __restrict__ y, const float* __restrict__ wt_sa1,
    const float* __restrict__ sa_w2, const float* __restrict__ sa_w3,
    float* __restrict__ sa) {
  int b = blockIdx.y;
  int p0 = (blockIdx.x * 256 + threadIdx.x) * 2;
  const float* yp = y + (size_t)b * C_ * HW_ + p0;
  float t1a[16], t1b[16];
#pragma unroll
  for (int j = 0; j < 16; ++j) { t1a[j] = 0.f; t1b[j] = 0.f; }
  for (int i = 0; i < C_; ++i) {
    float2 v = *(const float2*)(yp + (size_t)i * HW_);
    const float* wr = wt_sa1 + i * 16;   // uniform -> s_load
#pragma unroll
    for (int j = 0; j < 16; ++j) { t1a[j] = fmaf(wr[j], v.x, t1a[j]); t1b[j] = fmaf(wr[j], v.y, t1b[j]); }
  }
#pragma unroll
  for (int j = 0; j < 16; ++j) { t1a[j] = fmaxf(t1a[j], 0.f); t1b[j] = fmaxf(t1b[j], 0.f); }
  float t2a[16], t2b[16];
#pragma unroll
  for (int j = 0; j < 16; ++j) {
    float sx = 0.f, sy = 0.f;
#pragma unroll
    for (int l = 0; l < 16; ++l) { float w = sa_w2[j * 16 + l]; sx = fmaf(w, t1a[l], sx); sy = fmaf(w, t1b[l], sy); }
    t2a[j] = fmaxf(sx, 0.f); t2b[j] = fmaxf(sy, 0.f);
  }
  float sa3 = 0.f, sb3 = 0.f;
#pragma unroll
  for (int j = 0; j < 16; ++j) { float w = sa_w3[j]; sa3 = fmaf(w, t2a[j], sa3); sb3 = fmaf(w, t2b[j], sb3); }
  sa[(size_t)b * HW_ + p0]     = 1.f / (1.f + expf(-sa3));
  sa[(size_t)b * HW_ + p0 + 1] = 1.f / (1.f + expf(-sb3));
}

// -------------------------------- conv1x1 qkv via MFMA (split-bf16, big ws)
// C[384][HW] = W[384][128] * x[128][HW] per batch.
// x staged once per 64-pos tile, transposed to [p][k] (hi+lo residual split),
// XOR-swizzled rows; W_hi staged per 128-row m-block (pre-swizzled, linear).
// acc += A*B_hi; acc += A*B_lo  ->  error limited to W_lo*x (~2^-9 rel),
// below the existing bf16 quantization of `pre`.
__global__ void __launch_bounds__(256) k_convm(
    const float* __restrict__ x, const bf16* __restrict__ wbf, bf16* __restrict__ pre) {
  __shared__ bf16 XT[2][64][128];   // [hi/lo][p][k swizzled]  2 x 16 KB
  __shared__ bf16 AT[128][128];     // [o_local][k swizzled]   32 KB
  int b = blockIdx.y;
  int p0 = blockIdx.x * 64;
  int t = threadIdx.x;

  // ---- stage X tile: read f32 coalesced, split hi/lo, transpose+swizzle
  {
    int p  = t & 63;
    int c0 = t >> 6;                 // 4 threads share a p, 4 chunk-iters each
    const float* xp = x + (size_t)b * C_ * HW_ + p0 + p;
#pragma unroll
    for (int it = 0; it < 4; ++it) {
      int c = c0 + it * 4;           // k-chunk 0..15 (8 elems each)
      short8 hv, lv;
#pragma unroll
      for (int j = 0; j < 8; ++j) {
        float v = xp[(size_t)(c * 8 + j) * HW_];
        bf16 h = f2b(v);
        bf16 l = f2b(v - b2f(h));
        hv[j] = b2s(h); lv[j] = b2s(l);
      }
      int sc = c ^ (p & 7);
      *(short8*)&XT[0][p][sc * 8] = hv;
      *(short8*)&XT[1][p][sc * 8] = lv;
    }
  }

  int lane = t & 63, wave = t >> 6;
  int m = lane & 15, quad = lane >> 4;
  int wr = wave >> 1, wc = wave & 1;          // 2x2 wave grid (64M x 32N each)
  float4v acc[4][2];

  for (int mb = 0; mb < 3; ++mb) {
    __syncthreads();                 // prior compute done before AT overwrite
    {                                // linear conflict-free 32 KB copy
      const short8* src = (const short8*)(wbf + mb * C_ * C_);
      short8* dst = (short8*)&AT[0][0];
#pragma unroll
      for (int j = 0; j < 8; ++j)
        dst[j * 256 + t] = src[j * 256 + t];
    }
    __syncthreads();

#pragma unroll
    for (int mt = 0; mt < 4; ++mt)
#pragma unroll
      for (int nt = 0; nt < 2; ++nt)
#pragma unroll
        for (int e = 0; e < 4; ++e) acc[mt][nt][e] = 0.f;

#pragma unroll
    for (int kk = 0; kk < 4; ++kk) {
      int cidx = (((kk * 4 + quad) ^ (m & 7)) << 3);
      short8 af[4], bh[2], bl[2];
#pragma unroll
      for (int mt = 0; mt < 4; ++mt)
        af[mt] = *(const short8*)&AT[wr * 64 + mt * 16 + m][cidx];
#pragma unroll
      for (int nt = 0; nt < 2; ++nt) {
        bh[nt] = *(const short8*)&XT[0][wc * 32 + nt * 16 + m][cidx];
        bl[nt] = *(const short8*)&XT[1][wc * 32 + nt * 16 + m][cidx];
      }
#pragma unroll
      for (int mt = 0; mt < 4; ++mt)
#pragma unroll
        for (int nt = 0; nt < 2; ++nt) {
          acc[mt][nt] = __builtin_amdgcn_mfma_f32_16x16x32_bf16(af[mt], bh[nt], acc[mt][nt], 0, 0, 0);
          acc[mt][nt] = __builtin_amdgcn_mfma_f32_16x16x32_bf16(af[mt], bl[nt], acc[mt][nt], 0, 0, 0);
        }
    }

    // C layout: D[row=quad*4+reg][col=m]; rows are out-channels, cols positions
    bf16* op = pre + (size_t)b * C3_ * HW_ + (size_t)(mb * C_) * HW_ + p0;
#pragma unroll
    for (int mt = 0; mt < 4; ++mt)
#pragma unroll
      for (int nt = 0; nt < 2; ++nt)
#pragma unroll
        for (int reg = 0; reg < 4; ++reg) {
          int o = wr * 64 + mt * 16 + quad * 4 + reg;
          int p = wc * 32 + nt * 16 + m;
          op[(size_t)o * HW_ + p] = f2b(acc[mt][nt][reg]);
        }
  }
}

// ------------ dw3x3(q,k from pre) + sa-gate + gram via MFMA + ssq (big ws)
__global__ void __launch_bounds__(256) k_dwgram(
    const bf16* __restrict__ pre, const float* __restrict__ dww,
    const float* __restrict__ sa, float* __restrict__ attn_raw,
    float* __restrict__ ssq_q, float* __restrict__ ssq_k) {
  __shared__ char smem[65536];
  bf16 (*ring)[32][256] = (bf16 (*)[32][256])smem;          // 48 KB
  bf16 (*dwb)[256] = (bf16 (*)[256])(smem + 49152);         // 16 KB, XOR-swizzled
  float* red = (float*)smem;                                 // overlay (post-loop)

  int b = blockIdx.z, head = blockIdx.y, r0 = blockIdx.x * 8;
  int t = threadIdx.x;
  const bf16* preb = pre + (size_t)b * C3_ * HW_;
  const float* saw = sa + (size_t)b * HW_;

  auto loadrow = [&](int r) {
    int slot = (r + 3) % 3;
    if (r < 0 || r >= H_) {
#pragma unroll
      for (int c = 0; c < 32; ++c) ring[slot][c][t] = f2b(0.f);
      return;
    }
#pragma unroll
    for (int c = 0; c < 32; ++c) {
      int och = (c < 16) ? (head * CH_ + c) : (C_ + head * CH_ + c - 16);
      ring[slot][c][t] = preb[(size_t)och * HW_ + r * W_ + t];
    }
  };
  loadrow(r0 - 1); loadrow(r0); loadrow(r0 + 1);
  __syncthreads();

  int lane = t & 63, wave = t >> 6;
  int m = lane & 15, quad = lane >> 4;
  int srow = t & 31, schunk = t >> 5;
  float4v acc = {0.f, 0.f, 0.f, 0.f};
  float sacc = 0.f;

  for (int rr = r0; rr < r0 + 8; ++rr) {
    float gate = saw[rr * W_ + t];
#pragma unroll
    for (int ch = 0; ch < 32; ++ch) {
      int och = (ch < 16) ? (head * CH_ + ch) : (C_ + head * CH_ + ch - 16);
      const float* wp = dww + och * 9;   // uniform -> s_load
      float a = 0.f;
#pragma unroll
      for (int dy = -1; dy <= 1; ++dy) {
        int s = (rr + dy + 3) % 3;
#pragma unroll
        for (int dx = -1; dx <= 1; ++dx) {
          int cc = t + dx;
          if (cc < 0 || cc >= W_) continue;
          a = fmaf(wp[(dy + 1) * 3 + dx + 1], b2f(ring[s][ch][cc]), a);
        }
      }
      if (ch < 16) a *= gate;
      dwb[ch][t ^ ((ch & 7) << 3)] = f2b(a);
    }
    __syncthreads();
    // gram: 2 MFMA k-steps per wave (64 positions), acc carried across rr
#pragma unroll
    for (int cn = 0; cn < 2; ++cn) {
      int p0 = wave * 64 + cn * 32;
      int ca = ((((p0 >> 3) + quad) ^ (m & 7)) << 3);
      short8 af = *(const short8*)&dwb[m][ca];        // A: q rows
      short8 bfv = *(const short8*)&dwb[16 + m][ca];  // B: k rows
      acc = __builtin_amdgcn_mfma_f32_16x16x32_bf16(af, bfv, acc, 0, 0, 0);
    }
    // ssq: thread = (row srow, chunk schunk of 32 positions)
#pragma unroll
    for (int j = 0; j < 32; ++j) {
      int p = schunk * 32 + j;
      float v = b2f(dwb[srow][p ^ ((srow & 7) << 3)]);
      sacc = fmaf(v, v, sacc);
    }
    if (rr < r0 + 7) loadrow(rr + 2);
    __syncthreads();
  }
  // C layout: D[row=quad*4+reg][col=m] -> attn_raw[c=row][d=col]
  float* ar = attn_raw + ((size_t)b * HD_ + head) * 256;
#pragma unroll
  for (int reg = 0; reg < 4; ++reg)
    atomicAdd(&ar[(quad * 4 + reg) * 16 + m], acc[reg]);
  red[t] = sacc;
  __syncthreads();
  if (t < 32) {
    float s = 0.f;
#pragma unroll
    for (int k = 0; k < 8; ++k) s += red[t + 32 * k];
    if (t < 16) atomicAdd(&ssq_q[((size_t)b * HD_ + head) * CH_ + t], s);
    else        atomicAdd(&ssq_k[((size_t)b * HD_ + head) * CH_ + t - 16], s);
  }
}

// ----------------------------------------------- normalize + temp + softmax
__global__ void k_softmax(const float* __restrict__ attn_raw, const float* __restrict__ ssq_q,
                          const float* __restrict__ ssq_k, const float* __restrict__ temperature,
                          float* __restrict__ attn) {
  int row = threadIdx.x;              // 256 rows = (b, head, c)
  int bh = row >> 4;
  int head = bh & 7;
  float temp = temperature[head];
  float nq = fmaxf(sqrtf(ssq_q[row]), 1e-12f);
  float v[16];
#pragma unroll
  for (int d = 0; d < 16; ++d) {
    float nk = fmaxf(sqrtf(ssq_k[bh * 16 + d]), 1e-12f);
    v[d] = attn_raw[row * 16 + d] / (nq * nk) * temp;
  }
  float m = -1e30f;
#pragma unroll
  for (int d = 0; d < 16; ++d) m = fmaxf(m, v[d]);
  float s = 0.f;
#pragma unroll
  for (int d = 0; d < 16; ++d) { v[d] = expf(v[d] - m); s += v[d]; }
  float inv = 1.f / s;
#pragma unroll
  for (int d = 0; d < 16; ++d) attn[row * 16 + d] = v[d] * inv;
}

// ---------------- dw3x3(v from pre) + attn@v -> d_out f32 ("out") (big ws)
__global__ void __launch_bounds__(256) k_out(
    const bf16* __restrict__ pre, const float* __restrict__ dww,
    const float* __restrict__ attn, float* __restrict__ outb) {
  __shared__ bf16 ring[3][16][256];   // 24 KB
  int b = blockIdx.z, head = blockIdx.y, r0 = blockIdx.x * 8;
  int t = threadIdx.x;
  const bf16* preb = pre + (size_t)b * C3_ * HW_ + (size_t)(2 * C_ + head * CH_) * HW_;

  auto loadrow = [&](int r) {
    int slot = (r + 3) % 3;
    if (r < 0 || r >= H_) {
#pragma unroll
      for (int c = 0; c < 16; ++c) ring[slot][c][t] = f2b(0.f);
      return;
    }
#pragma unroll
    for (int c = 0; c < 16; ++c)
      ring[slot][c][t] = preb[(size_t)c * HW_ + r * W_ + t];
  };
  loadrow(r0 - 1); loadrow(r0); loadrow(r0 + 1);
  __syncthreads();
  const float* ap = attn + ((size_t)b * HD_ + head) * 256;   // uniform -> s_load
  for (int rr = r0; rr < r0 + 8; ++rr) {
    float vv[16];
#pragma unroll
    for (int ch = 0; ch < 16; ++ch) {
      int och = 2 * C_ + head * CH_ + ch;
      const float* wp = dww + och * 9;
      float a = 0.f;
#pragma unroll
      for (int dy = -1; dy <= 1; ++dy) {
        int s = (rr + dy + 3) % 3;
#pragma unroll
        for (int dx = -1; dx <= 1; ++dx) {
          int cc = t + dx;
          if (cc < 0 || cc >= W_) continue;
          a = fmaf(wp[(dy + 1) * 3 + dx + 1], b2f(ring[s][ch][cc]), a);
        }
      }
      vv[ch] = a;
    }
    float* op = outb + ((size_t)b * C_ + head * CH_) * (size_t)HW_ + rr * W_ + t;
#pragma unroll
    for (int c2 = 0; c2 < 16; ++c2) {
      float s = 0.f;
#pragma unroll
      for (int d = 0; d < 16; ++d) s = fmaf(ap[c2 * 16 + d], vv[d], s);
      op[(size_t)c2 * HW_] = s;
    }
    __syncthreads();
    if (rr < r0 + 7) loadrow(rr + 2);
    __syncthreads();
  }
}

// ------------------------------------------------------------------- pooling
__global__ void k_pool(const float* __restrict__ outb, float* __restrict__ pooled) {
  int ch = blockIdx.x, b = blockIdx.y;
  const float* p = outb + ((size_t)b * C_ + ch) * (size_t)HW_;
  float s = 0.f;
  for (int i = threadIdx.x * 4; i < HW_; i += 1024) {
    float4 v = *(const float4*)(p + i);
    s += v.x + v.y + v.z + v.w;
  }
#pragma unroll
  for (int off = 32; off > 0; off >>= 1) s += __shfl_down(s, off);
  __shared__ float wsum[4];
  int lane = threadIdx.x & 63, wv = threadIdx.x >> 6;
  if (lane == 0) wsum[wv] = s;
  __syncthreads();
  if (threadIdx.x == 0) {
    float tt = wsum[0] + wsum[1] + wsum[2] + wsum[3];
    pooled[b * C_ + ch] = tt * (1.f / HW_);
  }
}

// ------------------------------------------------------------- spectral gate
__global__ void k_spec(const float* __restrict__ pooled, const float* __restrict__ sp_w1,
                       const float* __restrict__ sp_w2, const float* __restrict__ sp_w3,
                       float* __restrict__ spec) {
  __shared__ float g1[2][16], g2[2][16];
  int tid = threadIdx.x;
  const float RS2 = 0.70710678118654752f;
  if (tid < 32) {
    int b = tid >> 4, j = tid & 15;
    float s = 0.f;
    for (int i = 0; i < C_; ++i) s = fmaf(sp_w1[j * C_ + i], pooled[b * C_ + i], s);
    g1[b][j] = 0.5f * s * (1.f + erff(s * RS2));
  }
  __syncthreads();
  if (tid < 32) {
    int b = tid >> 4, j = tid & 15;
    float s = 0.f;
    for (int l = 0; l < 16; ++l) s = fmaf(sp_w2[j * 16 + l], g1[b][l], s);
    g2[b][j] = 0.5f * s * (1.f + erff(s * RS2));
  }
  __syncthreads();
  {
    int b = tid >> 7, o = tid & 127;
    float s = 0.f;
    for (int jj = 0; jj < 16; ++jj) s = fmaf(sp_w3[o * 16 + jj], g2[b][jj], s);
    spec[b * C_ + o] = 1.f / (1.f + expf(-s));
  }
}

// ----------- elementwise: d_out += dw3x3(y) * spec  (float4, big ws path)
__global__ void __launch_bounds__(256) k_z(
    const float* __restrict__ y, const float* __restrict__ dww,
    const float* __restrict__ spec, float* __restrict__ dout) {
  int b = blockIdx.z, ch = blockIdx.y;
  int row = blockIdx.x * 4 + (threadIdx.x >> 6);
  int c0 = (threadIdx.x & 63) * 4;
  const float* yb = y + ((size_t)b * C_ + ch) * HW_;
  const float* wp = dww + ch * 9;   // uniform -> s_load
  float acc[4] = {0.f, 0.f, 0.f, 0.f};
#pragma unroll
  for (int dy = -1; dy <= 1; ++dy) {
    int rrow = row + dy;
    if (rrow < 0 || rrow >= H_) continue;
    const float* yr = yb + rrow * W_;
    float4 cv = *(const float4*)(yr + c0);
    float lf = (c0 > 0) ? yr[c0 - 1] : 0.f;
    float rt = (c0 + 4 < W_) ? yr[c0 + 4] : 0.f;
    float w0 = wp[(dy + 1) * 3], w1 = wp[(dy + 1) * 3 + 1], w2 = wp[(dy + 1) * 3 + 2];
    float v[6] = {lf, cv.x, cv.y, cv.z, cv.w, rt};
#pragma unroll
    for (int j = 0; j < 4; ++j)
      acc[j] = fmaf(w0, v[j], fmaf(w1, v[j + 1], fmaf(w2, v[j + 2], acc[j])));
  }
  float sp = spec[b * C_ + ch];
  float* dp = dout + ((size_t)b * C_ + ch) * HW_ + row * W_ + c0;
  float4 ov = *(const float4*)dp;
  ov.x += acc[0] * sp; ov.y += acc[1] * sp; ov.z += acc[2] * sp; ov.w += acc[3] * sp;
  *(float4*)dp = ov;
}

// --------------- proj 128x128 GEMM in-place on d_out (row-block, big ws path)
__global__ void __launch_bounds__(256) k_proj(
    const float* __restrict__ wt_proj, float* __restrict__ dout) {
  __shared__ bf16 zt[128][256];
  int b = blockIdx.y, r = blockIdx.x, t = threadIdx.x;
  float* db = dout + (size_t)b * C_ * HW_;
  for (int ch = 0; ch < C_; ++ch)
    zt[ch][t] = f2b(db[(size_t)ch * HW_ + r * W_ + t]);
  __syncthreads();
#pragma unroll
  for (int half = 0; half < 2; ++half) {
    float acc[64];
#pragma unroll
    for (int o = 0; o < 64; ++o) acc[o] = 0.f;
    for (int i = 0; i < C_; ++i) {
      float zv = b2f(zt[i][t]);
      const float* wr = wt_proj + i * C_ + half * 64;   // uniform -> s_load
#pragma unroll
      for (int o = 0; o < 64; ++o) acc[o] = fmaf(wr[o], zv, acc[o]);
    }
#pragma unroll
    for (int o = 0; o < 64; ++o)
      db[(size_t)(half * 64 + o) * HW_ + r * W_ + t] = acc[o];
  }
}

// ====================== fallback kernels (small ws): round-4 fused, f32 ======
__global__ void __launch_bounds__(256) k_gram_fb(
    const float* __restrict__ x, const float* __restrict__ wt_qkvT,
    const float* __restrict__ dww, const float* __restrict__ sa,
    float* __restrict__ attn_raw, float* __restrict__ ssq_q, float* __restrict__ ssq_k) {
  __shared__ bf16 ring[3][32][256];
  __shared__ bf16 dwb[32][256];
  int b = blockIdx.z, head = blockIdx.y, r0 = blockIdx.x * 8;
  int t = threadIdx.x;
  const float* xb = x + (size_t)b * C_ * HW_;
  const float* saw = sa + (size_t)b * HW_;
  auto convrow = [&](int r) {
    int slot = (r + 3) % 3;
    if (r < 0 || r >= H_) {
#pragma unroll
      for (int c = 0; c < 32; ++c) ring[slot][c][t] = f2b(0.f);
      return;
    }
    float acc[32];
#pragma unroll
    for (int c = 0; c < 32; ++c) acc[c] = 0.f;
    const float* xp = xb + r * W_ + t;
    const float* wq = wt_qkvT + head * CH_;
    const float* wk = wt_qkvT + C_ + head * CH_;
    for (int i = 0; i < C_; ++i) {
      float xv = xp[(size_t)i * HW_];
      const float* w1 = wq + i * C3_;
      const float* w2 = wk + i * C3_;
#pragma unroll
      for (int c = 0; c < 16; ++c) acc[c]      = fmaf(w1[c], xv, acc[c]);
#pragma unroll
      for (int c = 0; c < 16; ++c) acc[16 + c] = fmaf(w2[c], xv, acc[16 + c]);
    }
#pragma unroll
    for (int c = 0; c < 32; ++c) ring[slot][c][t] = f2b(acc[c]);
  };
  convrow(r0 - 1); convrow(r0); convrow(r0 + 1);
  __syncthreads();
  int c = t >> 4, d = t & 15;
  float gacc = 0.f, sacc = 0.f;
  for (int rr = r0; rr < r0 + 8; ++rr) {
    float gate = saw[rr * W_ + t];
    for (int ch = 0; ch < 32; ++ch) {
      int och = (ch < 16) ? (head * CH_ + ch) : (C_ + head * CH_ + ch - 16);
      float a = 0.f;
#pragma unroll
      for (int dy = -1; dy <= 1; ++dy) {
        int s = (rr + dy + 3) % 3;
#pragma unroll
        for (int dx = -1; dx <= 1; ++dx) {
          int cc = t + dx;
          if (cc < 0 || cc >= W_) continue;
          a = fmaf(dww[och * 9 + (dy + 1) * 3 + dx + 1], b2f(ring[s][ch][cc]), a);
        }
      }
      if (ch < 16) a *= gate;
      dwb[ch][t] = f2b(a);
    }
    __syncthreads();
    for (int p = 0; p < 256; ++p) {
      int pp = (p + 4 * d + 2 * c) & 255;
      gacc = fmaf(b2f(dwb[c][pp]), b2f(dwb[16 + d][pp]), gacc);
    }
    if (t < 32) {
      for (int p = 0; p < 256; ++p) {
        int pp = (p + 2 * t) & 255;
        float v = b2f(dwb[t][pp]);
        sacc = fmaf(v, v, sacc);
      }
    }
    if (rr < r0 + 7) convrow(rr + 2);
    __syncthreads();
  }
  atomicAdd(&attn_raw[(((size_t)b * HD_ + head) * CH_ + c) * CH_ + d], gacc);
  if (t < 16)      atomicAdd(&ssq_q[((size_t)b * HD_ + head) * CH_ + t], sacc);
  else if (t < 32) atomicAdd(&ssq_k[((size_t)b * HD_ + head) * CH_ + t - 16], sacc);
}

__global__ void __launch_bounds__(256) k_out_fb(
    const float* __restrict__ x, const float* __restrict__ wt_qkvT,
    const float* __restrict__ dww, const float* __restrict__ attn,
    float* __restrict__ outb) {
  __shared__ bf16 ring[3][16][256];
  int b = blockIdx.z, head = blockIdx.y, r0 = blockIdx.x * 8;
  int t = threadIdx.x;
  const float* xb = x + (size_t)b * C_ * HW_;
  auto convrow = [&](int r) {
    int slot = (r + 3) % 3;
    if (r < 0 || r >= H_) {
#pragma unroll
      for (int c = 0; c < 16; ++c) ring[slot][c][t] = f2b(0.f);
      return;
    }
    float acc[16];
#pragma unroll
    for (int c = 0; c < 16; ++c) acc[c] = 0.f;
    const float* xp = xb + r * W_ + t;
    const float* wv = wt_qkvT + 2 * C_ + head * CH_;
    for (int i = 0; i < C_; ++i) {
      float xv = xp[(size_t)i * HW_];
      const float* w1 = wv + i * C3_;
#pragma unroll
      for (int c = 0; c < 16; ++c) acc[c] = fmaf(w1[c], xv, acc[c]);
    }
#pragma unroll
    for (int c = 0; c < 16; ++c) ring[slot][c][t] = f2b(acc[c]);
  };
  convrow(r0 - 1); convrow(r0); convrow(r0 + 1);
  __syncthreads();
  const float* ap = attn + ((size_t)b * HD_ + head) * 256;
  for (int rr = r0; rr < r0 + 8; ++rr) {
    float vv[16];
#pragma unroll
    for (int ch = 0; ch < 16; ++ch) {
      int och = 2 * C_ + head * CH_ + ch;
      float a = 0.f;
#pragma unroll
      for (int dy = -1; dy <= 1; ++dy) {
        int s = (rr + dy + 3) % 3;
#pragma unroll
        for (int dx = -1; dx <= 1; ++dx) {
          int cc = t + dx;
          if (cc < 0 || cc >= W_) continue;
          a = fmaf(dww[och * 9 + (dy + 1) * 3 + dx + 1], b2f(ring[s][ch][cc]), a);
        }
      }
      vv[ch] = a;
    }
    float* op = outb + ((size_t)b * C_ + head * CH_) * (size_t)HW_ + rr * W_ + t;
#pragma unroll
    for (int c2 = 0; c2 < 16; ++c2) {
      float s = 0.f;
#pragma unroll
      for (int d = 0; d < 16; ++d) s = fmaf(ap[c2 * 16 + d], vv[d], s);
      op[(size_t)c2 * HW_] = s;
    }
    __syncthreads();
    if (rr < r0 + 7) convrow(rr + 2);
    __syncthreads();
  }
}

__global__ void __launch_bounds__(256) k_zproj_fb(
    const float* __restrict__ y, const float* __restrict__ dwwz,
    const float* __restrict__ spec, const float* __restrict__ wt_proj,
    float* __restrict__ dout) {
  __shared__ bf16 zt[128][256];
  int b = blockIdx.y, r = blockIdx.x;
  int t = threadIdx.x;
  const float* yb = y + (size_t)b * C_ * HW_;
  float* db = dout + (size_t)b * C_ * HW_;
  for (int ch = 0; ch < C_; ++ch) {
    float a = 0.f;
#pragma unroll
    for (int dy = -1; dy <= 1; ++dy) {
      int hh = r + dy;
      if (hh < 0 || hh >= H_) continue;
      const float* row = yb + (size_t)ch * HW_ + hh * W_;
#pragma unroll
      for (int dx = -1; dx <= 1; ++dx) {
        int cc = t + dx;
        if (cc < 0 || cc >= W_) continue;
        a = fmaf(dwwz[ch * 9 + (dy + 1) * 3 + dx + 1], row[cc], a);
      }
    }
    float z = db[(size_t)ch * HW_ + r * W_ + t] + a * spec[b * C_ + ch];
    zt[ch][t] = f2b(z);
  }
  __syncthreads();
#pragma unroll
  for (int half = 0; half < 2; ++half) {
    float acc[64];
#pragma unroll
    for (int o = 0; o < 64; ++o) acc[o] = 0.f;
    for (int i = 0; i < C_; ++i) {
      float zv = b2f(zt[i][t]);
      const float* wr = wt_proj + i * C_ + half * 64;
#pragma unroll
      for (int o = 0; o < 64; ++o) acc[o] = fmaf(wr[o], zv, acc[o]);
    }
#pragma unroll
    for (int o = 0; o < 64; ++o)
      db[(size_t)(half * 64 + o) * HW_ + r * W_ + t] = acc[o];
  }
}

// ---------------------------------------------------------------------------
extern "C" void kernel_launch(void* const* d_in, const int* in_sizes, int n_in,
                              void* d_out, int out_size, void* d_ws, size_t ws_size,
                              hipStream_t stream) {
  const float* x        = (const float*)d_in[0];
  const float* y        = (const float*)d_in[1];
  const float* qkv_w    = (const float*)d_in[2];
  const float* qkv_dw_w = (const float*)d_in[3];
  const float* proj_w   = (const float*)d_in[4];
  const float* sa_w1    = (const float*)d_in[5];
  const float* sa_w2    = (const float*)d_in[6];
  const float* sa_w3    = (const float*)d_in[7];
  const float* sp_w1    = (const float*)d_in[8];
  const float* sp_w2    = (const float*)d_in[9];
  const float* sp_w3    = (const float*)d_in[10];
  const float* dw_w     = (const float*)d_in[11];
  const float* temp     = (const float*)d_in[12];
  float* out = (float*)d_out;

  char* ws = (char*)d_ws;
  float* attn_raw = (float*)(ws + 0);         // 4096 f32
  float* ssq_q    = (float*)(ws + 16384);     // 256 f32
  float* ssq_k    = (float*)(ws + 17408);     // 256 f32
  float* attn     = (float*)(ws + 18432);     // 4096 f32
  float* pooled   = (float*)(ws + 34816);     // 256 f32
  float* spec     = (float*)(ws + 35840);     // 256 f32
  float* wt_qkvT  = (float*)(ws + 36864);     // [128][384] f32
  float* wt_proj  = (float*)(ws + 233472);    // [128][128] f32
  float* wt_sa1   = (float*)(ws + 299008);    // [128][16] f32
  float* sa       = (float*)(ws + 307200);    // [2][65536] f32 -> 831488
  bf16*  wt_qkv_bf= (bf16*) (ws + 835584);    // [384][128] bf16 swizzled -> 933888
  bf16*  pre      = (bf16*) (ws + 1048576);   // [2][384][65536] bf16 = 100663296
  const size_t NEED = 1048576 + 100663296;    // 101,711,872
  bool big = ws_size >= NEED;

  hipMemsetAsync(ws, 0, 18432, stream);       // attn_raw + ssq_q + ssq_k

  k_wprep<<<192, 256, 0, stream>>>(qkv_w, proj_w, sa_w1, wt_qkvT, wt_proj, wt_sa1,
                                   wt_qkv_bf, big ? 1 : 0);
  k_sa<<<dim3(HW_ / 512, B_), 256, 0, stream>>>(y, wt_sa1, sa_w2, sa_w3, sa);
  if (big) {
    k_convm<<<dim3(HW_ / 64, B_), 256, 0, stream>>>(x, wt_qkv_bf, pre);
    k_dwgram<<<dim3(H_ / 8, HD_, B_), 256, 0, stream>>>(pre, qkv_dw_w, sa,
                                                        attn_raw, ssq_q, ssq_k);
    k_softmax<<<1, 256, 0, stream>>>(attn_raw, ssq_q, ssq_k, temp, attn);
    k_out<<<dim3(H_ / 8, HD_, B_), 256, 0, stream>>>(pre, qkv_dw_w, attn, out);
  } else {
    k_gram_fb<<<dim3(H_ / 8, HD_, B_), 256, 0, stream>>>(x, wt_qkvT, qkv_dw_w, sa,
                                                         attn_raw, ssq_q, ssq_k);
    k_softmax<<<1, 256, 0, stream>>>(attn_raw, ssq_q, ssq_k, temp, attn);
    k_out_fb<<<dim3(H_ / 8, HD_, B_), 256, 0, stream>>>(x, wt_qkvT, qkv_dw_w, attn, out);
  }
  k_pool<<<dim3(C_, B_), 256, 0, stream>>>(out, pooled);
  k_spec<<<1, 256, 0, stream>>>(pooled, sp_w1, sp_w2, sp_w3, spec);
  if (big) {
    k_z<<<dim3(H_ / 4, C_, B_), 256, 0, stream>>>(y, dw_w, spec, out);
    k_proj<<<dim3(H_, B_), 256, 0, stream>>>(wt_proj, out);
  } else {
    k_zproj_fb<<<dim3(H_, B_), 256, 0, stream>>>(y, dw_w, spec, wt_proj, out);
  }
}

// Round 2
// 451.217 us; speedup vs baseline: 1.8215x; 1.3154x over previous
//
#include <hip/hip_runtime.h>
#include <hip/hip_bf16.h>

typedef __hip_bfloat16 bf16;
typedef __attribute__((ext_vector_type(8))) short short8;
typedef __attribute__((ext_vector_type(4))) int   int4v;
typedef __attribute__((ext_vector_type(4))) float float4v;

#define B_   2
#define C_   128
#define H_   256
#define W_   256
#define HW_  65536
#define HD_  8
#define CH_  16
#define C3_  384

static __device__ __forceinline__ float b2f(bf16 v) { return __bfloat162float(v); }
static __device__ __forceinline__ bf16  f2b(float v) { return __float2bfloat16(v); }
static __device__ __forceinline__ short b2s(bf16 v) { return *reinterpret_cast<short*>(&v); }
// bf16 (as raw short) -> f32: exact, just a shift
static __device__ __forceinline__ float su2f(short s) {
  return __uint_as_float(((unsigned)(unsigned short)s) << 16);
}
// AND all 128 bits of a short8 with a broadcast dword mask (0 or -1)
static __device__ __forceinline__ short8 smask(short8 v, int m) {
  int4v iv = *(int4v*)&v;
  iv = iv & m;
  return *(short8*)&iv;
}

// ---------------------------------------------------------------- weight prep
// qkv + proj weights as bf16, layout [o][k] with the gram-style XOR swizzle
// baked in (chunk ^= (o&7)) so GEMM kernels' A-tile stage is a linear copy.
__global__ void k_wprep(const float* __restrict__ qkv_w, const float* __restrict__ proj_w,
                        const float* __restrict__ sa_w1,
                        float* __restrict__ wt_qkvT, float* __restrict__ wt_proj,
                        float* __restrict__ wt_sa1, bf16* __restrict__ wt_qkv_bf,
                        bf16* __restrict__ wt_proj_bf, int do_bf) {
  int idx = blockIdx.x * 256 + threadIdx.x;
  if (idx < C3_ * C_) { int o = idx / C_, i = idx % C_; wt_qkvT[i * C3_ + o] = qkv_w[idx]; }
  if (idx < C_ * C_)  { int o = idx / C_, i = idx % C_; wt_proj[i * C_ + o] = proj_w[idx]; }
  if (idx < 16 * C_)  { int j = idx / C_, i = idx % C_; wt_sa1[i * 16 + j] = sa_w1[idx]; }
  if (do_bf && idx < C3_ * C_) {
    int o = idx / C_, k = idx % C_;
    int sk = ((((k >> 3) ^ (o & 7)) << 3) | (k & 7));
    wt_qkv_bf[o * C_ + sk] = f2b(qkv_w[idx]);
  }
  if (do_bf && idx < C_ * C_) {
    int o = idx / C_, k = idx % C_;
    int sk = ((((k >> 3) ^ (o & 7)) << 3) | (k & 7));
    wt_proj_bf[o * C_ + sk] = f2b(proj_w[idx]);
  }
}

// ------------------------------------------------- spatial gate sa (2 pos/thr)
__global__ void __launch_bounds__(256) k_sa(
    const float* __restrict__ y, const float* __restrict__ wt_sa1,
    const float* __restrict__ sa_w2, const float* __restrict__ sa_w3,
    float* __restrict__ sa) {
  int b = blockIdx.y;
  int p0 = (blockIdx.x * 256 + threadIdx.x) * 2;
  const float* yp = y + (size_t)b * C_ * HW_ + p0;
  float t1a[16], t1b[16];
#pragma unroll
  for (int j = 0; j < 16; ++j) { t1a[j] = 0.f; t1b[j] = 0.f; }
  for (int i = 0; i < C_; ++i) {
    float2 v = *(const float2*)(yp + (size_t)i * HW_);
    const float* wr = wt_sa1 + i * 16;   // uniform -> s_load
#pragma unroll
    for (int j = 0; j < 16; ++j) { t1a[j] = fmaf(wr[j], v.x, t1a[j]); t1b[j] = fmaf(wr[j], v.y, t1b[j]); }
  }
#pragma unroll
  for (int j = 0; j < 16; ++j) { t1a[j] = fmaxf(t1a[j], 0.f); t1b[j] = fmaxf(t1b[j], 0.f); }
  float t2a[16], t2b[16];
#pragma unroll
  for (int j = 0; j < 16; ++j) {
    float sx = 0.f, sy = 0.f;
#pragma unroll
    for (int l = 0; l < 16; ++l) { float w = sa_w2[j * 16 + l]; sx = fmaf(w, t1a[l], sx); sy = fmaf(w, t1b[l], sy); }
    t2a[j] = fmaxf(sx, 0.f); t2b[j] = fmaxf(sy, 0.f);
  }
  float sa3 = 0.f, sb3 = 0.f;
#pragma unroll
  for (int j = 0; j < 16; ++j) { float w = sa_w3[j]; sa3 = fmaf(w, t2a[j], sa3); sb3 = fmaf(w, t2b[j], sb3); }
  sa[(size_t)b * HW_ + p0]     = 1.f / (1.f + expf(-sa3));
  sa[(size_t)b * HW_ + p0 + 1] = 1.f / (1.f + expf(-sb3));
}

// -------------------------------- conv1x1 qkv via MFMA (split-bf16, big ws)
__global__ void __launch_bounds__(256) k_convm(
    const float* __restrict__ x, const bf16* __restrict__ wbf, bf16* __restrict__ pre) {
  __shared__ bf16 XT[2][64][128];   // [hi/lo][p][k swizzled]  2 x 16 KB
  __shared__ bf16 AT[128][128];     // [o_local][k swizzled]   32 KB
  int b = blockIdx.y;
  int p0 = blockIdx.x * 64;
  int t = threadIdx.x;

  {
    int p  = t & 63;
    int c0 = t >> 6;
    const float* xp = x + (size_t)b * C_ * HW_ + p0 + p;
#pragma unroll
    for (int it = 0; it < 4; ++it) {
      int c = c0 + it * 4;
      short8 hv, lv;
#pragma unroll
      for (int j = 0; j < 8; ++j) {
        float v = xp[(size_t)(c * 8 + j) * HW_];
        bf16 h = f2b(v);
        bf16 l = f2b(v - b2f(h));
        hv[j] = b2s(h); lv[j] = b2s(l);
      }
      int sc = c ^ (p & 7);
      *(short8*)&XT[0][p][sc * 8] = hv;
      *(short8*)&XT[1][p][sc * 8] = lv;
    }
  }

  int lane = t & 63, wave = t >> 6;
  int m = lane & 15, quad = lane >> 4;
  int wr = wave >> 1, wc = wave & 1;
  float4v acc[4][2];

  for (int mb = 0; mb < 3; ++mb) {
    __syncthreads();
    {
      const short8* src = (const short8*)(wbf + mb * C_ * C_);
      short8* dst = (short8*)&AT[0][0];
#pragma unroll
      for (int j = 0; j < 8; ++j)
        dst[j * 256 + t] = src[j * 256 + t];
    }
    __syncthreads();

#pragma unroll
    for (int mt = 0; mt < 4; ++mt)
#pragma unroll
      for (int nt = 0; nt < 2; ++nt)
#pragma unroll
        for (int e = 0; e < 4; ++e) acc[mt][nt][e] = 0.f;

#pragma unroll
    for (int kk = 0; kk < 4; ++kk) {
      int cidx = (((kk * 4 + quad) ^ (m & 7)) << 3);
      short8 af[4], bh[2], bl[2];
#pragma unroll
      for (int mt = 0; mt < 4; ++mt)
        af[mt] = *(const short8*)&AT[wr * 64 + mt * 16 + m][cidx];
#pragma unroll
      for (int nt = 0; nt < 2; ++nt) {
        bh[nt] = *(const short8*)&XT[0][wc * 32 + nt * 16 + m][cidx];
        bl[nt] = *(const short8*)&XT[1][wc * 32 + nt * 16 + m][cidx];
      }
#pragma unroll
      for (int mt = 0; mt < 4; ++mt)
#pragma unroll
        for (int nt = 0; nt < 2; ++nt) {
          acc[mt][nt] = __builtin_amdgcn_mfma_f32_16x16x32_bf16(af[mt], bh[nt], acc[mt][nt], 0, 0, 0);
          acc[mt][nt] = __builtin_amdgcn_mfma_f32_16x16x32_bf16(af[mt], bl[nt], acc[mt][nt], 0, 0, 0);
        }
    }

    bf16* op = pre + (size_t)b * C3_ * HW_ + (size_t)(mb * C_) * HW_ + p0;
#pragma unroll
    for (int mt = 0; mt < 4; ++mt)
#pragma unroll
      for (int nt = 0; nt < 2; ++nt)
#pragma unroll
        for (int reg = 0; reg < 4; ++reg) {
          int o = wr * 64 + mt * 16 + quad * 4 + reg;
          int p = wc * 32 + nt * 16 + m;
          op[(size_t)o * HW_ + p] = f2b(acc[mt][nt][reg]);
        }
  }
}

// ------------ dw3x3(q,k from pre) + sa-gate + gram via MFMA + ssq (big ws)
// ring layout [slot][ch-group][col][8ch]: one ds_read_b128 = 8 channels/tap,
// lane-contiguous (conflict-free). Edge cols via clamped addr + AND-mask.
__global__ void __launch_bounds__(256) k_dwgram(
    const bf16* __restrict__ pre, const float* __restrict__ dww,
    const float* __restrict__ sa, float* __restrict__ attn_raw,
    float* __restrict__ ssq_q, float* __restrict__ ssq_k) {
  __shared__ char smem[65536];
  bf16 (*ring)[4][256][8] = (bf16 (*)[4][256][8])smem;      // 48 KB
  bf16 (*dwb)[256] = (bf16 (*)[256])(smem + 49152);         // 16 KB, XOR-swizzled
  float* red = (float*)smem;                                 // overlay (post-loop)

  int b = blockIdx.z, head = blockIdx.y, r0 = blockIdx.x * 8;
  int t = threadIdx.x;
  const bf16* preb = pre + (size_t)b * C3_ * HW_;
  const float* saw = sa + (size_t)b * HW_;

  auto loadrow = [&](int r) {
    int slot = (r + 3) % 3;
#pragma unroll
    for (int cg = 0; cg < 4; ++cg) {
      short8 hv;
      if (r < 0 || r >= H_) {
#pragma unroll
        for (int j = 0; j < 8; ++j) hv[j] = 0;
      } else {
#pragma unroll
        for (int j = 0; j < 8; ++j) {
          int c = cg * 8 + j;
          int och = (c < 16) ? (head * CH_ + c) : (C_ + head * CH_ + c - 16);
          hv[j] = b2s(preb[(size_t)och * HW_ + r * W_ + t]);
        }
      }
      *(short8*)&ring[slot][cg][t][0] = hv;
    }
  };
  loadrow(r0 - 1); loadrow(r0); loadrow(r0 + 1);
  __syncthreads();

  int lane = t & 63, wave = t >> 6;
  int m = lane & 15, quad = lane >> 4;
  int sch = t >> 3;                    // ssq channel 0..31
  int ccl = (t > 0) ? (t - 1) : 0;
  int ccr = (t < W_ - 1) ? (t + 1) : (W_ - 1);
  int mskl = (t > 0) ? -1 : 0;
  int mskr = (t < W_ - 1) ? -1 : 0;
  float4v acc = {0.f, 0.f, 0.f, 0.f};
  float sacc = 0.f;

  for (int rr = r0; rr < r0 + 8; ++rr) {
    float gate = saw[rr * W_ + t];
    float a[32];
#pragma unroll
    for (int c = 0; c < 32; ++c) a[c] = 0.f;
#pragma unroll
    for (int dy = -1; dy <= 1; ++dy) {
      int s = (rr + dy + 3) % 3;
#pragma unroll
      for (int cg = 0; cg < 4; ++cg) {
        const bf16* base = &ring[s][cg][0][0];
        short8 vl = smask(*(const short8*)(base + ccl * 8), mskl);
        short8 vc = *(const short8*)(base + (size_t)t * 8);
        short8 vr = smask(*(const short8*)(base + ccr * 8), mskr);
#pragma unroll
        for (int j = 0; j < 8; ++j) {
          int c = cg * 8 + j;
          int och = (c < 16) ? (head * CH_ + c) : (C_ + head * CH_ + c - 16);
          const float* wp = dww + och * 9 + (dy + 1) * 3;   // uniform -> s_load
          a[c] = fmaf(wp[0], su2f(vl[j]), a[c]);
          a[c] = fmaf(wp[1], su2f(vc[j]), a[c]);
          a[c] = fmaf(wp[2], su2f(vr[j]), a[c]);
        }
      }
    }
#pragma unroll
    for (int c = 0; c < 16; ++c) a[c] *= gate;
#pragma unroll
    for (int c = 0; c < 32; ++c) dwb[c][t ^ ((c & 7) << 3)] = f2b(a[c]);
    __syncthreads();
    // gram: 2 MFMA k-steps per wave (64 positions), acc carried across rr
#pragma unroll
    for (int cn = 0; cn < 2; ++cn) {
      int p0 = wave * 64 + cn * 32;
      int ca = ((((p0 >> 3) + quad) ^ (m & 7)) << 3);
      short8 af = *(const short8*)&dwb[m][ca];        // A: q rows
      short8 bfv = *(const short8*)&dwb[16 + m][ca];  // B: k rows
      acc = __builtin_amdgcn_mfma_f32_16x16x32_bf16(af, bfv, acc, 0, 0, 0);
    }
    // ssq: thread = (channel t>>3, chunks (t&7)+8*it), vectorized b128 reads
#pragma unroll
    for (int it = 0; it < 4; ++it) {
      int c = (t & 7) + it * 8;
      int cs = c ^ (sch & 7);
      short8 v = *(const short8*)&dwb[sch][cs * 8];
#pragma unroll
      for (int j = 0; j < 8; ++j) { float f = su2f(v[j]); sacc = fmaf(f, f, sacc); }
    }
    if (rr < r0 + 7) loadrow(rr + 2);
    __syncthreads();
  }
  // C layout: D[row=quad*4+reg][col=m] -> attn_raw[c=row][d=col]
  float* ar = attn_raw + ((size_t)b * HD_ + head) * 256;
#pragma unroll
  for (int reg = 0; reg < 4; ++reg)
    atomicAdd(&ar[(quad * 4 + reg) * 16 + m], acc[reg]);
  red[t] = sacc;
  __syncthreads();
  if (t < 32) {
    float s = 0.f;
#pragma unroll
    for (int k = 0; k < 8; ++k) s += red[t * 8 + k];
    if (t < 16) atomicAdd(&ssq_q[((size_t)b * HD_ + head) * CH_ + t], s);
    else        atomicAdd(&ssq_k[((size_t)b * HD_ + head) * CH_ + t - 16], s);
  }
}

// ----------------------------------------------- normalize + temp + softmax
__global__ void k_softmax(const float* __restrict__ attn_raw, const float* __restrict__ ssq_q,
                          const float* __restrict__ ssq_k, const float* __restrict__ temperature,
                          float* __restrict__ attn) {
  int row = threadIdx.x;              // 256 rows = (b, head, c)
  int bh = row >> 4;
  int head = bh & 7;
  float temp = temperature[head];
  float nq = fmaxf(sqrtf(ssq_q[row]), 1e-12f);
  float v[16];
#pragma unroll
  for (int d = 0; d < 16; ++d) {
    float nk = fmaxf(sqrtf(ssq_k[bh * 16 + d]), 1e-12f);
    v[d] = attn_raw[row * 16 + d] / (nq * nk) * temp;
  }
  float m = -1e30f;
#pragma unroll
  for (int d = 0; d < 16; ++d) m = fmaxf(m, v[d]);
  float s = 0.f;
#pragma unroll
  for (int d = 0; d < 16; ++d) { v[d] = expf(v[d] - m); s += v[d]; }
  float inv = 1.f / s;
#pragma unroll
  for (int d = 0; d < 16; ++d) attn[row * 16 + d] = v[d] * inv;
}

// ---------------- dw3x3(v from pre) + attn@v -> d_out f32 ("out") (big ws)
__global__ void __launch_bounds__(256) k_out(
    const bf16* __restrict__ pre, const float* __restrict__ dww,
    const float* __restrict__ attn, float* __restrict__ outb) {
  __shared__ bf16 ring[3][2][256][8];   // 24 KB, [slot][cg][col][8ch]
  int b = blockIdx.z, head = blockIdx.y, r0 = blockIdx.x * 8;
  int t = threadIdx.x;
  const bf16* preb = pre + (size_t)b * C3_ * HW_ + (size_t)(2 * C_ + head * CH_) * HW_;

  auto loadrow = [&](int r) {
    int slot = (r + 3) % 3;
#pragma unroll
    for (int cg = 0; cg < 2; ++cg) {
      short8 hv;
      if (r < 0 || r >= H_) {
#pragma unroll
        for (int j = 0; j < 8; ++j) hv[j] = 0;
      } else {
#pragma unroll
        for (int j = 0; j < 8; ++j)
          hv[j] = b2s(preb[(size_t)(cg * 8 + j) * HW_ + r * W_ + t]);
      }
      *(short8*)&ring[slot][cg][t][0] = hv;
    }
  };
  loadrow(r0 - 1); loadrow(r0); loadrow(r0 + 1);
  __syncthreads();
  const float* ap = attn + ((size_t)b * HD_ + head) * 256;   // uniform -> s_load
  int ccl = (t > 0) ? (t - 1) : 0;
  int ccr = (t < W_ - 1) ? (t + 1) : (W_ - 1);
  int mskl = (t > 0) ? -1 : 0;
  int mskr = (t < W_ - 1) ? -1 : 0;
  for (int rr = r0; rr < r0 + 8; ++rr) {
    float vv[16];
#pragma unroll
    for (int c = 0; c < 16; ++c) vv[c] = 0.f;
#pragma unroll
    for (int dy = -1; dy <= 1; ++dy) {
      int s = (rr + dy + 3) % 3;
#pragma unroll
      for (int cg = 0; cg < 2; ++cg) {
        const bf16* base = &ring[s][cg][0][0];
        short8 vl = smask(*(const short8*)(base + ccl * 8), mskl);
        short8 vc = *(const short8*)(base + (size_t)t * 8);
        short8 vr = smask(*(const short8*)(base + ccr * 8), mskr);
#pragma unroll
        for (int j = 0; j < 8; ++j) {
          int c = cg * 8 + j;
          const float* wp = dww + (2 * C_ + head * CH_ + c) * 9 + (dy + 1) * 3;
          vv[c] = fmaf(wp[0], su2f(vl[j]), vv[c]);
          vv[c] = fmaf(wp[1], su2f(vc[j]), vv[c]);
          vv[c] = fmaf(wp[2], su2f(vr[j]), vv[c]);
        }
      }
    }
    float* op = outb + ((size_t)b * C_ + head * CH_) * (size_t)HW_ + rr * W_ + t;
#pragma unroll
    for (int c2 = 0; c2 < 16; ++c2) {
      float s2 = 0.f;
#pragma unroll
      for (int d = 0; d < 16; ++d) s2 = fmaf(ap[c2 * 16 + d], vv[d], s2);
      op[(size_t)c2 * HW_] = s2;
    }
    __syncthreads();
    if (rr < r0 + 7) loadrow(rr + 2);
    __syncthreads();
  }
}

// ------------------------------------------------------------------- pooling
__global__ void k_pool(const float* __restrict__ outb, float* __restrict__ pooled) {
  int ch = blockIdx.x, b = blockIdx.y;
  const float* p = outb + ((size_t)b * C_ + ch) * (size_t)HW_;
  float s = 0.f;
  for (int i = threadIdx.x * 4; i < HW_; i += 1024) {
    float4 v = *(const float4*)(p + i);
    s += v.x + v.y + v.z + v.w;
  }
#pragma unroll
  for (int off = 32; off > 0; off >>= 1) s += __shfl_down(s, off);
  __shared__ float wsum[4];
  int lane = threadIdx.x & 63, wv = threadIdx.x >> 6;
  if (lane == 0) wsum[wv] = s;
  __syncthreads();
  if (threadIdx.x == 0) {
    float tt = wsum[0] + wsum[1] + wsum[2] + wsum[3];
    pooled[b * C_ + ch] = tt * (1.f / HW_);
  }
}

// ------------------------------------------------------------- spectral gate
__global__ void k_spec(const float* __restrict__ pooled, const float* __restrict__ sp_w1,
                       const float* __restrict__ sp_w2, const float* __restrict__ sp_w3,
                       float* __restrict__ spec) {
  __shared__ float g1[2][16], g2[2][16];
  int tid = threadIdx.x;
  const float RS2 = 0.70710678118654752f;
  if (tid < 32) {
    int b = tid >> 4, j = tid & 15;
    float s = 0.f;
    for (int i = 0; i < C_; ++i) s = fmaf(sp_w1[j * C_ + i], pooled[b * C_ + i], s);
    g1[b][j] = 0.5f * s * (1.f + erff(s * RS2));
  }
  __syncthreads();
  if (tid < 32) {
    int b = tid >> 4, j = tid & 15;
    float s = 0.f;
    for (int l = 0; l < 16; ++l) s = fmaf(sp_w2[j * 16 + l], g1[b][l], s);
    g2[b][j] = 0.5f * s * (1.f + erff(s * RS2));
  }
  __syncthreads();
  {
    int b = tid >> 7, o = tid & 127;
    float s = 0.f;
    for (int jj = 0; jj < 16; ++jj) s = fmaf(sp_w3[o * 16 + jj], g2[b][jj], s);
    spec[b * C_ + o] = 1.f / (1.f + expf(-s));
  }
}

// ----------- elementwise: d_out += dw3x3(y) * spec  (float4, big ws path)
__global__ void __launch_bounds__(256) k_z(
    const float* __restrict__ y, const float* __restrict__ dww,
    const float* __restrict__ spec, float* __restrict__ dout) {
  int b = blockIdx.z, ch = blockIdx.y;
  int row = blockIdx.x * 4 + (threadIdx.x >> 6);
  int c0 = (threadIdx.x & 63) * 4;
  const float* yb = y + ((size_t)b * C_ + ch) * HW_;
  const float* wp = dww + ch * 9;   // uniform -> s_load
  float acc[4] = {0.f, 0.f, 0.f, 0.f};
#pragma unroll
  for (int dy = -1; dy <= 1; ++dy) {
    int rrow = row + dy;
    if (rrow < 0 || rrow >= H_) continue;
    const float* yr = yb + rrow * W_;
    float4 cv = *(const float4*)(yr + c0);
    float lf = (c0 > 0) ? yr[c0 - 1] : 0.f;
    float rt = (c0 + 4 < W_) ? yr[c0 + 4] : 0.f;
    float w0 = wp[(dy + 1) * 3], w1 = wp[(dy + 1) * 3 + 1], w2 = wp[(dy + 1) * 3 + 2];
    float v[6] = {lf, cv.x, cv.y, cv.z, cv.w, rt};
#pragma unroll
    for (int j = 0; j < 4; ++j)
      acc[j] = fmaf(w0, v[j], fmaf(w1, v[j + 1], fmaf(w2, v[j + 2], acc[j])));
  }
  float sp = spec[b * C_ + ch];
  float* dp = dout + ((size_t)b * C_ + ch) * HW_ + row * W_ + c0;
  float4 ov = *(const float4*)dp;
  ov.x += acc[0] * sp; ov.y += acc[1] * sp; ov.z += acc[2] * sp; ov.w += acc[3] * sp;
  *(float4*)dp = ov;
}

// --------------- proj 128x128 GEMM via MFMA, in-place on d_out (big ws)
// same structure as k_convm: split-bf16 z (hi+lo), pre-swizzled bf16 weights.
__global__ void __launch_bounds__(256) k_projm(
    const bf16* __restrict__ wpb, float* __restrict__ dout) {
  __shared__ bf16 XT[2][64][128];   // [hi/lo][p][k swizzled]  2 x 16 KB
  __shared__ bf16 AT[128][128];     // [o][k swizzled]         32 KB
  int b = blockIdx.y;
  int p0 = blockIdx.x * 64;
  int t = threadIdx.x;

  {
    const short8* src = (const short8*)wpb;
    short8* dst = (short8*)&AT[0][0];
#pragma unroll
    for (int j = 0; j < 8; ++j)
      dst[j * 256 + t] = src[j * 256 + t];
  }
  {
    int p  = t & 63;
    int c0 = t >> 6;
    const float* xp = dout + (size_t)b * C_ * HW_ + p0 + p;
#pragma unroll
    for (int it = 0; it < 4; ++it) {
      int c = c0 + it * 4;
      short8 hv, lv;
#pragma unroll
      for (int j = 0; j < 8; ++j) {
        float v = xp[(size_t)(c * 8 + j) * HW_];
        bf16 h = f2b(v);
        bf16 l = f2b(v - b2f(h));
        hv[j] = b2s(h); lv[j] = b2s(l);
      }
      int sc = c ^ (p & 7);
      *(short8*)&XT[0][p][sc * 8] = hv;
      *(short8*)&XT[1][p][sc * 8] = lv;
    }
  }
  __syncthreads();

  int lane = t & 63, wave = t >> 6;
  int m = lane & 15, quad = lane >> 4;
  int wr = wave >> 1, wc = wave & 1;
  float4v acc[4][2];
#pragma unroll
  for (int mt = 0; mt < 4; ++mt)
#pragma unroll
    for (int nt = 0; nt < 2; ++nt)
#pragma unroll
      for (int e = 0; e < 4; ++e) acc[mt][nt][e] = 0.f;

#pragma unroll
  for (int kk = 0; kk < 4; ++kk) {
    int cidx = (((kk * 4 + quad) ^ (m & 7)) << 3);
    short8 af[4], bh[2], bl[2];
#pragma unroll
    for (int mt = 0; mt < 4; ++mt)
      af[mt] = *(const short8*)&AT[wr * 64 + mt * 16 + m][cidx];
#pragma unroll
    for (int nt = 0; nt < 2; ++nt) {
      bh[nt] = *(const short8*)&XT[0][wc * 32 + nt * 16 + m][cidx];
      bl[nt] = *(const short8*)&XT[1][wc * 32 + nt * 16 + m][cidx];
    }
#pragma unroll
    for (int mt = 0; mt < 4; ++mt)
#pragma unroll
      for (int nt = 0; nt < 2; ++nt) {
        acc[mt][nt] = __builtin_amdgcn_mfma_f32_16x16x32_bf16(af[mt], bh[nt], acc[mt][nt], 0, 0, 0);
        acc[mt][nt] = __builtin_amdgcn_mfma_f32_16x16x32_bf16(af[mt], bl[nt], acc[mt][nt], 0, 0, 0);
      }
  }

  float* op = dout + (size_t)b * C_ * HW_ + p0;
#pragma unroll
  for (int mt = 0; mt < 4; ++mt)
#pragma unroll
    for (int nt = 0; nt < 2; ++nt)
#pragma unroll
      for (int reg = 0; reg < 4; ++reg) {
        int o = wr * 64 + mt * 16 + quad * 4 + reg;
        int p = wc * 32 + nt * 16 + m;
        op[(size_t)o * HW_ + p] = acc[mt][nt][reg];
      }
}

// ====================== fallback kernels (small ws): round-4 fused, f32 ======
__global__ void __launch_bounds__(256) k_gram_fb(
    const float* __restrict__ x, const float* __restrict__ wt_qkvT,
    const float* __restrict__ dww, const float* __restrict__ sa,
    float* __restrict__ attn_raw, float* __restrict__ ssq_q, float* __restrict__ ssq_k) {
  __shared__ bf16 ring[3][32][256];
  __shared__ bf16 dwb[32][256];
  int b = blockIdx.z, head = blockIdx.y, r0 = blockIdx.x * 8;
  int t = threadIdx.x;
  const float* xb = x + (size_t)b * C_ * HW_;
  const float* saw = sa + (size_t)b * HW_;
  auto convrow = [&](int r) {
    int slot = (r + 3) % 3;
    if (r < 0 || r >= H_) {
#pragma unroll
      for (int c = 0; c < 32; ++c) ring[slot][c][t] = f2b(0.f);
      return;
    }
    float acc[32];
#pragma unroll
    for (int c = 0; c < 32; ++c) acc[c] = 0.f;
    const float* xp = xb + r * W_ + t;
    const float* wq = wt_qkvT + head * CH_;
    const float* wk = wt_qkvT + C_ + head * CH_;
    for (int i = 0; i < C_; ++i) {
      float xv = xp[(size_t)i * HW_];
      const float* w1 = wq + i * C3_;
      const float* w2 = wk + i * C3_;
#pragma unroll
      for (int c = 0; c < 16; ++c) acc[c]      = fmaf(w1[c], xv, acc[c]);
#pragma unroll
      for (int c = 0; c < 16; ++c) acc[16 + c] = fmaf(w2[c], xv, acc[16 + c]);
    }
#pragma unroll
    for (int c = 0; c < 32; ++c) ring[slot][c][t] = f2b(acc[c]);
  };
  convrow(r0 - 1); convrow(r0); convrow(r0 + 1);
  __syncthreads();
  int c = t >> 4, d = t & 15;
  float gacc = 0.f, sacc = 0.f;
  for (int rr = r0; rr < r0 + 8; ++rr) {
    float gate = saw[rr * W_ + t];
    for (int ch = 0; ch < 32; ++ch) {
      int och = (ch < 16) ? (head * CH_ + ch) : (C_ + head * CH_ + ch - 16);
      float a = 0.f;
#pragma unroll
      for (int dy = -1; dy <= 1; ++dy) {
        int s = (rr + dy + 3) % 3;
#pragma unroll
        for (int dx = -1; dx <= 1; ++dx) {
          int cc = t + dx;
          if (cc < 0 || cc >= W_) continue;
          a = fmaf(dww[och * 9 + (dy + 1) * 3 + dx + 1], b2f(ring[s][ch][cc]), a);
        }
      }
      if (ch < 16) a *= gate;
      dwb[ch][t] = f2b(a);
    }
    __syncthreads();
    for (int p = 0; p < 256; ++p) {
      int pp = (p + 4 * d + 2 * c) & 255;
      gacc = fmaf(b2f(dwb[c][pp]), b2f(dwb[16 + d][pp]), gacc);
    }
    if (t < 32) {
      for (int p = 0; p < 256; ++p) {
        int pp = (p + 2 * t) & 255;
        float v = b2f(dwb[t][pp]);
        sacc = fmaf(v, v, sacc);
      }
    }
    if (rr < r0 + 7) convrow(rr + 2);
    __syncthreads();
  }
  atomicAdd(&attn_raw[(((size_t)b * HD_ + head) * CH_ + c) * CH_ + d], gacc);
  if (t < 16)      atomicAdd(&ssq_q[((size_t)b * HD_ + head) * CH_ + t], sacc);
  else if (t < 32) atomicAdd(&ssq_k[((size_t)b * HD_ + head) * CH_ + t - 16], sacc);
}

__global__ void __launch_bounds__(256) k_out_fb(
    const float* __restrict__ x, const float* __restrict__ wt_qkvT,
    const float* __restrict__ dww, const float* __restrict__ attn,
    float* __restrict__ outb) {
  __shared__ bf16 ring[3][16][256];
  int b = blockIdx.z, head = blockIdx.y, r0 = blockIdx.x * 8;
  int t = threadIdx.x;
  const float* xb = x + (size_t)b * C_ * HW_;
  auto convrow = [&](int r) {
    int slot = (r + 3) % 3;
    if (r < 0 || r >= H_) {
#pragma unroll
      for (int c = 0; c < 16; ++c) ring[slot][c][t] = f2b(0.f);
      return;
    }
    float acc[16];
#pragma unroll
    for (int c = 0; c < 16; ++c) acc[c] = 0.f;
    const float* xp = xb + r * W_ + t;
    const float* wv = wt_qkvT + 2 * C_ + head * CH_;
    for (int i = 0; i < C_; ++i) {
      float xv = xp[(size_t)i * HW_];
      const float* w1 = wv + i * C3_;
#pragma unroll
      for (int c = 0; c < 16; ++c) acc[c] = fmaf(w1[c], xv, acc[c]);
    }
#pragma unroll
    for (int c = 0; c < 16; ++c) ring[slot][c][t] = f2b(acc[c]);
  };
  convrow(r0 - 1); convrow(r0); convrow(r0 + 1);
  __syncthreads();
  const float* ap = attn + ((size_t)b * HD_ + head) * 256;
  for (int rr = r0; rr < r0 + 8; ++rr) {
    float vv[16];
#pragma unroll
    for (int ch = 0; ch < 16; ++ch) {
      int och = 2 * C_ + head * CH_ + ch;
      float a = 0.f;
#pragma unroll
      for (int dy = -1; dy <= 1; ++dy) {
        int s = (rr + dy + 3) % 3;
#pragma unroll
        for (int dx = -1; dx <= 1; ++dx) {
          int cc = t + dx;
          if (cc < 0 || cc >= W_) continue;
          a = fmaf(dww[och * 9 + (dy + 1) * 3 + dx + 1], b2f(ring[s][ch][cc]), a);
        }
      }
      vv[ch] = a;
    }
    float* op = outb + ((size_t)b * C_ + head * CH_) * (size_t)HW_ + rr * W_ + t;
#pragma unroll
    for (int c2 = 0; c2 < 16; ++c2) {
      float s = 0.f;
#pragma unroll
      for (int d = 0; d < 16; ++d) s = fmaf(ap[c2 * 16 + d], vv[d], s);
      op[(size_t)c2 * HW_] = s;
    }
    __syncthreads();
    if (rr < r0 + 7) convrow(rr + 2);
    __syncthreads();
  }
}

__global__ void __launch_bounds__(256) k_zproj_fb(
    const float* __restrict__ y, const float* __restrict__ dwwz,
    const float* __restrict__ spec, const float* __restrict__ wt_proj,
    float* __restrict__ dout) {
  __shared__ bf16 zt[128][256];
  int b = blockIdx.y, r = blockIdx.x;
  int t = threadIdx.x;
  const float* yb = y + (size_t)b * C_ * HW_;
  float* db = dout + (size_t)b * C_ * HW_;
  for (int ch = 0; ch < C_; ++ch) {
    float a = 0.f;
#pragma unroll
    for (int dy = -1; dy <= 1; ++dy) {
      int hh = r + dy;
      if (hh < 0 || hh >= H_) continue;
      const float* row = yb + (size_t)ch * HW_ + hh * W_;
#pragma unroll
      for (int dx = -1; dx <= 1; ++dx) {
        int cc = t + dx;
        if (cc < 0 || cc >= W_) continue;
        a = fmaf(dwwz[ch * 9 + (dy + 1) * 3 + dx + 1], row[cc], a);
      }
    }
    float z = db[(size_t)ch * HW_ + r * W_ + t] + a * spec[b * C_ + ch];
    zt[ch][t] = f2b(z);
  }
  __syncthreads();
#pragma unroll
  for (int half = 0; half < 2; ++half) {
    float acc[64];
#pragma unroll
    for (int o = 0; o < 64; ++o) acc[o] = 0.f;
    for (int i = 0; i < C_; ++i) {
      float zv = b2f(zt[i][t]);
      const float* wr = wt_proj + i * C_ + half * 64;
#pragma unroll
      for (int o = 0; o < 64; ++o) acc[o] = fmaf(wr[o], zv, acc[o]);
    }
#pragma unroll
    for (int o = 0; o < 64; ++o)
      db[(size_t)(half * 64 + o) * HW_ + r * W_ + t] = acc[o];
  }
}

// ---------------------------------------------------------------------------
extern "C" void kernel_launch(void* const* d_in, const int* in_sizes, int n_in,
                              void* d_out, int out_size, void* d_ws, size_t ws_size,
                              hipStream_t stream) {
  const float* x        = (const float*)d_in[0];
  const float* y        = (const float*)d_in[1];
  const float* qkv_w    = (const float*)d_in[2];
  const float* qkv_dw_w = (const float*)d_in[3];
  const float* proj_w   = (const float*)d_in[4];
  const float* sa_w1    = (const float*)d_in[5];
  const float* sa_w2    = (const float*)d_in[6];
  const float* sa_w3    = (const float*)d_in[7];
  const float* sp_w1    = (const float*)d_in[8];
  const float* sp_w2    = (const float*)d_in[9];
  const float* sp_w3    = (const float*)d_in[10];
  const float* dw_w     = (const float*)d_in[11];
  const float* temp     = (const float*)d_in[12];
  float* out = (float*)d_out;

  char* ws = (char*)d_ws;
  float* attn_raw = (float*)(ws + 0);         // 4096 f32
  float* ssq_q    = (float*)(ws + 16384);     // 256 f32
  float* ssq_k    = (float*)(ws + 17408);     // 256 f32
  float* attn     = (float*)(ws + 18432);     // 4096 f32
  float* pooled   = (float*)(ws + 34816);     // 256 f32
  float* spec     = (float*)(ws + 35840);     // 256 f32
  float* wt_qkvT  = (float*)(ws + 36864);     // [128][384] f32
  float* wt_proj  = (float*)(ws + 233472);    // [128][128] f32
  float* wt_sa1   = (float*)(ws + 299008);    // [128][16] f32
  float* sa       = (float*)(ws + 307200);    // [2][65536] f32 -> 831488
  bf16*  wt_qkv_bf = (bf16*)(ws + 835584);    // [384][128] bf16 swizzled -> 933888
  bf16*  wt_proj_bf= (bf16*)(ws + 933888);    // [128][128] bf16 swizzled -> 966656
  bf16*  pre      = (bf16*) (ws + 1048576);   // [2][384][65536] bf16 = 100663296
  const size_t NEED = 1048576 + 100663296;    // 101,711,872
  bool big = ws_size >= NEED;

  hipMemsetAsync(ws, 0, 18432, stream);       // attn_raw + ssq_q + ssq_k

  k_wprep<<<192, 256, 0, stream>>>(qkv_w, proj_w, sa_w1, wt_qkvT, wt_proj, wt_sa1,
                                   wt_qkv_bf, wt_proj_bf, big ? 1 : 0);
  k_sa<<<dim3(HW_ / 512, B_), 256, 0, stream>>>(y, wt_sa1, sa_w2, sa_w3, sa);
  if (big) {
    k_convm<<<dim3(HW_ / 64, B_), 256, 0, stream>>>(x, wt_qkv_bf, pre);
    k_dwgram<<<dim3(H_ / 8, HD_, B_), 256, 0, stream>>>(pre, qkv_dw_w, sa,
                                                        attn_raw, ssq_q, ssq_k);
    k_softmax<<<1, 256, 0, stream>>>(attn_raw, ssq_q, ssq_k, temp, attn);
    k_out<<<dim3(H_ / 8, HD_, B_), 256, 0, stream>>>(pre, qkv_dw_w, attn, out);
  } else {
    k_gram_fb<<<dim3(H_ / 8, HD_, B_), 256, 0, stream>>>(x, wt_qkvT, qkv_dw_w, sa,
                                                         attn_raw, ssq_q, ssq_k);
    k_softmax<<<1, 256, 0, stream>>>(attn_raw, ssq_q, ssq_k, temp, attn);
    k_out_fb<<<dim3(H_ / 8, HD_, B_), 256, 0, stream>>>(x, wt_qkvT, qkv_dw_w, attn, out);
  }
  k_pool<<<dim3(C_, B_), 256, 0, stream>>>(out, pooled);
  k_spec<<<1, 256, 0, stream>>>(pooled, sp_w1, sp_w2, sp_w3, spec);
  if (big) {
    k_z<<<dim3(H_ / 4, C_, B_), 256, 0, stream>>>(y, dw_w, spec, out);
    k_projm<<<dim3(HW_ / 64, B_), 256, 0, stream>>>(wt_proj_bf, out);
  } else {
    k_zproj_fb<<<dim3(H_, B_), 256, 0, stream>>>(y, dw_w, spec, wt_proj, out);
  }
}